// Round 2
// baseline (540.292 us; speedup 1.0000x reference)
//
#include <hip/hip_runtime.h>
#include <hip/hip_bf16.h>
#include <stdint.h>

#define NNODE 17
#define CIN 128
#define COUT 128
#define NBATCH 16384
#define ROWS (NBATCH*NNODE)          // 278528
#define ROWS_PER_BLK 128
#define NBLK (ROWS/ROWS_PER_BLK)     // 2176
#define KTOT 384                     // 3*CIN
#define THREADS 256                  // 4 waves, 2 M-tiles each

typedef __attribute__((ext_vector_type(8))) short short8;
typedef __attribute__((ext_vector_type(4))) float f32x4;
typedef __attribute__((ext_vector_type(4))) unsigned int uint4v;

static __device__ __forceinline__ unsigned short f2bf(float f){
  union { float f; unsigned int u; } v; v.f = f;
  unsigned int r = v.u + 0x7fffu + ((v.u >> 16) & 1u);   // RNE
  return (unsigned short)(r >> 16);
}
static __device__ __forceinline__ float bflo(unsigned int u){
  union { unsigned int u; float f; } v; v.u = u << 16; return v.f;
}
static __device__ __forceinline__ float bfhi(unsigned int u){
  union { unsigned int u; float f; } v; v.u = u & 0xffff0000u; return v.f;
}
// LDS XOR-swizzle: spreads 256B-strided rows across 8 16B slots (kills 16-way conflict).
// Applied identically on write and read (bijective involution, bits 4-6).
static __device__ __forceinline__ int swz(int a){ return a ^ (((a >> 8) & 7) << 4); }

// ---- prep 1: Chebyshev basis T[3][17][17] (f32) ----
__global__ void prep_cheb(const float* __restrict__ adj, float* __restrict__ Tws){
  __shared__ float dinv[NNODE];
  __shared__ float Lsh[NNODE*NNODE];
  int t = threadIdx.x;
  if (t < NNODE){
    float s = 0.f;
    for (int m = 0; m < NNODE; m++) s += adj[t*NNODE + m];
    dinv[t] = rsqrtf(s);
  }
  __syncthreads();
  if (t < NNODE*NNODE){
    int n = t / NNODE, m = t - n*NNODE;
    float l = ((n == m) ? 1.f : 0.f) - dinv[n] * adj[t] * dinv[m];
    Lsh[t] = l;
    Tws[t] = (n == m) ? 1.f : 0.f;      // T0 = I
    Tws[289 + t] = l;                   // T1 = L
  }
  __syncthreads();
  if (t < NNODE*NNODE){
    int n = t / NNODE, m = t - n*NNODE;
    float s = 0.f;
    for (int p = 0; p < NNODE; p++) s += Lsh[n*NNODE + p] * Lsh[p*NNODE + m];
    Tws[2*289 + t] = 2.f*s - ((n == m) ? 1.f : 0.f);   // T2 = 2L^2 - I
  }
}

// ---- prep 2: Wt[d][k*128+c] = bf16(W[k][0][c][d]) : [128][384] bf16 ----
__global__ void prep_w(const float* __restrict__ w, unsigned short* __restrict__ wt){
  int i = blockIdx.x * blockDim.x + threadIdx.x;   // 0..49151
  int d = i / KTOT;
  int kc = i - d*KTOT;
  wt[i] = f2bf(w[kc*COUT + d]);
}

// ---- main fused kernel ----
// 256 threads = 4 waves; block owns 128 rows; each wave owns TWO 16-row M-tiles
// (amortizes Wt B-fragment loads 2x). x for <=9 batches staged in LDS as bf16
// (XOR-swizzled). k=0 (T0=I) feeds x directly as A-frags; k=1,2 aggregate in
// f32 VALU from LDS then round to bf16 A-frags. mfma_f32_16x16x32_bf16.
__global__ __launch_bounds__(THREADS) void cheb_main(
    const float* __restrict__ x, const float* __restrict__ bias,
    const float* __restrict__ Tws, const unsigned short* __restrict__ Wt,
    float* __restrict__ out)
{
  __shared__ __align__(16) unsigned short xs[9*NNODE*CIN];   // 39168 B
  __shared__ float Ts[3*NNODE*NNODE];                        // 3468 B

  const int tid = threadIdx.x;
  const int r0blk = blockIdx.x * ROWS_PER_BLK;
  const unsigned b_lo = (unsigned)r0blk / 17u;
  const unsigned b_hi = (unsigned)(r0blk + ROWS_PER_BLK - 1) / 17u;
  const int nb = (int)(b_hi - b_lo) + 1;                     // <= 9

  // stage x[b_lo..b_hi] -> LDS bf16, swizzled
  const int nvec = nb * (NNODE*CIN/4);                       // nb*544 float4
  const float4* gx = (const float4*)(x + (size_t)b_lo * (NNODE*CIN));
  for (int i = tid; i < nvec; i += THREADS){
    float4 v = gx[i];
    ushort4 p;
    p.x = f2bf(v.x); p.y = f2bf(v.y); p.z = f2bf(v.z); p.w = f2bf(v.w);
    *(ushort4*)((char*)xs + swz(i*8)) = p;
  }
  for (int i = tid; i < 3*NNODE*NNODE; i += THREADS) Ts[i] = Tws[i];
  __syncthreads();

  const int lane = tid & 63;
  const int wv   = tid >> 6;             // 0..3
  const int l15  = lane & 15;
  const int lg   = lane >> 4;            // 0..3 (k-subgroup)
  const int csub = lg * 8;
  const int row0 = r0blk + wv*32;        // this wave's first M-tile row

  const unsigned rA0 = (unsigned)(row0 + l15);
  const unsigned rA1 = (unsigned)(row0 + 16 + l15);
  const unsigned bA0 = rA0 / 17u, bA1 = rA1 / 17u;
  const int nA0 = (int)(rA0 - bA0*17u), nA1 = (int)(rA1 - bA1*17u);
  const int xb0 = (int)(bA0 - b_lo) * (NNODE*CIN);
  const int xb1 = (int)(bA1 - b_lo) * (NNODE*CIN);
  const int ra0 = xb0 + nA0*CIN;         // own-row element offset
  const int ra1 = xb1 + nA1*CIN;

  f32x4 acc0[8], acc1[8];
  #pragma unroll
  for (int ct = 0; ct < 8; ct++){
    acc0[ct] = (f32x4){0.f,0.f,0.f,0.f};
    acc1[ct] = (f32x4){0.f,0.f,0.f,0.f};
  }

  // ---- k = 0: T0 = I, A-frag = x rows directly ----
  #pragma unroll
  for (int kk4 = 0; kk4 < 4; kk4++){
    const int c0 = kk4*32 + csub;
    short8 af0 = *(const short8*)((const char*)xs + swz((ra0 + c0)*2));
    short8 af1 = *(const short8*)((const char*)xs + swz((ra1 + c0)*2));
    const unsigned short* wp = Wt + kk4*32 + csub;
    #pragma unroll
    for (int ct = 0; ct < 8; ct++){
      short8 bf = *(const short8*)&wp[(ct*16 + l15)*KTOT];
      acc0[ct] = __builtin_amdgcn_mfma_f32_16x16x32_bf16(af0, bf, acc0[ct], 0, 0, 0);
      acc1[ct] = __builtin_amdgcn_mfma_f32_16x16x32_bf16(af1, bf, acc1[ct], 0, 0, 0);
    }
  }

  // ---- k = 1,2: VALU aggregation then MFMA ----
  #pragma unroll 1
  for (int k = 1; k < 3; k++){
    float tv0[NNODE], tv1[NNODE];
    #pragma unroll
    for (int m = 0; m < NNODE; m++){
      tv0[m] = Ts[k*289 + nA0*NNODE + m];
      tv1[m] = Ts[k*289 + nA1*NNODE + m];
    }
    #pragma unroll 1
    for (int kk4 = 0; kk4 < 4; kk4++){
      const int c0 = kk4*32 + csub;
      float f0[8], f1[8];
      #pragma unroll
      for (int j = 0; j < 8; j++){ f0[j] = 0.f; f1[j] = 0.f; }
      #pragma unroll
      for (int m = 0; m < NNODE; m++){
        uint4v xv0 = *(const uint4v*)((const char*)xs + swz((xb0 + m*CIN + c0)*2));
        uint4v xv1 = *(const uint4v*)((const char*)xs + swz((xb1 + m*CIN + c0)*2));
        const float t0 = tv0[m], t1 = tv1[m];
        #pragma unroll
        for (int jj = 0; jj < 4; jj++){
          unsigned int u0 = xv0[jj], u1 = xv1[jj];
          f0[2*jj]   += t0 * bflo(u0);
          f0[2*jj+1] += t0 * bfhi(u0);
          f1[2*jj]   += t1 * bflo(u1);
          f1[2*jj+1] += t1 * bfhi(u1);
        }
      }
      short8 af0, af1;
      #pragma unroll
      for (int j = 0; j < 8; j++){
        af0[j] = (short)f2bf(f0[j]);
        af1[j] = (short)f2bf(f1[j]);
      }
      const unsigned short* wp = Wt + (k*4 + kk4)*32 + csub;
      #pragma unroll
      for (int ct = 0; ct < 8; ct++){
        short8 bf = *(const short8*)&wp[(ct*16 + l15)*KTOT];
        acc0[ct] = __builtin_amdgcn_mfma_f32_16x16x32_bf16(af0, bf, acc0[ct], 0, 0, 0);
        acc1[ct] = __builtin_amdgcn_mfma_f32_16x16x32_bf16(af1, bf, acc1[ct], 0, 0, 0);
      }
    }
  }

  // ---- epilogue: bias + relu + store ----
  // C/D layout (m89-verified): col = lane&15 (output channel), row = lg*4 + i
  const int rb0 = row0 + lg*4;
  const int rb1 = row0 + 16 + lg*4;
  #pragma unroll
  for (int ct = 0; ct < 8; ct++){
    const int d = ct*16 + l15;
    const float bi = bias[d];
    #pragma unroll
    for (int i = 0; i < 4; i++){
      float v0 = acc0[ct][i] + bi;
      float v1 = acc1[ct][i] + bi;
      out[(size_t)(rb0 + i)*COUT + d] = v0 > 0.f ? v0 : 0.f;
      out[(size_t)(rb1 + i)*COUT + d] = v1 > 0.f ? v1 : 0.f;
    }
  }
}

extern "C" void kernel_launch(void* const* d_in, const int* in_sizes, int n_in,
                              void* d_out, int out_size, void* d_ws, size_t ws_size,
                              hipStream_t stream){
  const float* x    = (const float*)d_in[0];
  const float* adj  = (const float*)d_in[1];
  const float* w    = (const float*)d_in[2];
  const float* bias = (const float*)d_in[3];
  float* out = (float*)d_out;

  float* Tws = (float*)d_ws;                                    // 867 f32
  unsigned short* Wt = (unsigned short*)((char*)d_ws + 4096);   // 128*384 bf16 = 96KB

  hipLaunchKernelGGL(prep_cheb, dim3(1), dim3(320), 0, stream, adj, Tws);
  hipLaunchKernelGGL(prep_w, dim3(96), dim3(512), 0, stream, w, Wt);
  hipLaunchKernelGGL(cheb_main, dim3(NBLK), dim3(THREADS), 0, stream, x, bias, Tws, Wt, out);
}

// Round 3
// 339.074 us; speedup vs baseline: 1.5934x; 1.5934x over previous
//
#include <hip/hip_runtime.h>
#include <hip/hip_bf16.h>
#include <stdint.h>

#define NNODE 17
#define CIN 128
#define COUT 128
#define NBATCH 16384
#define ROWS (NBATCH*NNODE)          // 278528
#define ROWS_PER_BLK 128
#define NBLK (ROWS/ROWS_PER_BLK)     // 2176
#define THREADS 256                  // 4 waves x 32 rows = 128 rows/block

typedef __attribute__((ext_vector_type(8))) short short8;
typedef __attribute__((ext_vector_type(16))) float f32x16;
typedef __attribute__((ext_vector_type(4))) unsigned int uint4v;

static __device__ __forceinline__ unsigned short f2bf(float f){
  union { float f; unsigned int u; } v; v.f = f;
  unsigned int r = v.u + 0x7fffu + ((v.u >> 16) & 1u);   // RNE
  return (unsigned short)(r >> 16);
}
static __device__ __forceinline__ float bflo(unsigned int u){
  union { unsigned int u; float f; } v; v.u = u << 16; return v.f;
}
static __device__ __forceinline__ float bfhi(unsigned int u){
  union { unsigned int u; float f; } v; v.u = u & 0xffff0000u; return v.f;
}
// LDS XOR-swizzle (involution on bits 4-6 keyed by row bits 8-10); 16B-alignment preserving.
static __device__ __forceinline__ int swz(int a){ return a ^ (((a >> 8) & 7) << 4); }

// ---- merged prep: W2 fragment-linear (all blocks) + Chebyshev basis (block 0) ----
// W2 layout: for kslice ks (k=ks/8, c0=(ks%8)*16), ct (0..3), lane l (0..63), j (0..7):
//   W2[((ks*4+ct)*64 + l)*8 + j] = bf16( W[k][0][c0 + (l>>5)*8 + j][ct*32 + (l&31)] )
// so a wave's B-frag load is lane-linear: 16 B per lane, 1 KB contiguous per frag.
__global__ void prep_all(const float* __restrict__ adj, const float* __restrict__ w,
                         float* __restrict__ Tws, unsigned short* __restrict__ w2){
  const int tid = threadIdx.x;
  const int gi = blockIdx.x * 512 + tid;          // 0..49151
  {
    const int j  = gi & 7;
    const int l  = (gi >> 3) & 63;
    const int ct = (gi >> 9) & 3;
    const int ks = gi >> 11;                      // 0..23
    const int k  = ks >> 3;
    const int c  = (ks & 7)*16 + (l >> 5)*8 + j;
    const int d  = ct*32 + (l & 31);
    w2[gi] = f2bf(w[(k*CIN + c)*COUT + d]);
  }
  if (blockIdx.x != 0) return;

  __shared__ float dinv[NNODE];
  __shared__ float Lsh[NNODE*NNODE];
  if (tid < NNODE){
    float s = 0.f;
    for (int m = 0; m < NNODE; m++) s += adj[tid*NNODE + m];
    dinv[tid] = rsqrtf(s);
  }
  __syncthreads();
  if (tid < NNODE*NNODE){
    int n = tid / NNODE, m = tid - n*NNODE;
    float l = ((n == m) ? 1.f : 0.f) - dinv[n] * adj[tid] * dinv[m];
    Lsh[tid] = l;
    Tws[tid] = (n == m) ? 1.f : 0.f;              // T0 = I (unused by main, kept for clarity)
    Tws[289 + tid] = l;                           // T1 = L
  }
  __syncthreads();
  if (tid < NNODE*NNODE){
    int n = tid / NNODE, m = tid - n*NNODE;
    float s = 0.f;
    for (int p = 0; p < NNODE; p++) s += Lsh[n*NNODE + p] * Lsh[p*NNODE + m];
    Tws[2*289 + tid] = 2.f*s - ((n == m) ? 1.f : 0.f);   // T2 = 2L^2 - I
  }
}

// ---- main fused kernel ----
// 4 waves; wave owns 32 rows (one 32x32x16 M-tile), all 128 output cols (acc 4 x f32x16).
// x staged in LDS bf16 (swizzled). Per 16-channel slice s:
//   k0 A-frag = own x row (1 LDS read); k1,k2 A-frags aggregated in f32 VALU from a
//   SINGLE x pass (reads are LDS broadcasts across lanes of the same batch);
//   B-frags = coalesced 1KB global loads from fragment-linear W2 (L2-resident).
__global__ __launch_bounds__(THREADS) void cheb_main(
    const float* __restrict__ x, const float* __restrict__ bias,
    const float* __restrict__ Tws, const unsigned short* __restrict__ W2,
    float* __restrict__ out)
{
  __shared__ __align__(16) unsigned short xs[9*NNODE*CIN];   // 39168 B

  const int tid = threadIdx.x;
  const int r0blk = blockIdx.x * ROWS_PER_BLK;
  const unsigned b_lo = (unsigned)r0blk / 17u;
  const unsigned b_hi = (unsigned)(r0blk + ROWS_PER_BLK - 1) / 17u;
  const int nb = (int)(b_hi - b_lo) + 1;                     // <= 9

  // stage x[b_lo..b_hi] -> LDS bf16, swizzled (coalesced float4 loads, b64 writes)
  const int nvec = nb * (NNODE*CIN/4);
  const float4* gx = (const float4*)(x + (size_t)b_lo * (NNODE*CIN));
  for (int i = tid; i < nvec; i += THREADS){
    float4 v = gx[i];
    ushort4 p;
    p.x = f2bf(v.x); p.y = f2bf(v.y); p.z = f2bf(v.z); p.w = f2bf(v.w);
    *(ushort4*)((char*)xs + swz(i*8)) = p;
  }

  const int lane = tid & 63;
  const int wv   = tid >> 6;             // 0..3
  const int h    = lane >> 5;            // 0/1: k-half of A/B frags
  const int row  = r0blk + wv*32 + (lane & 31);
  const unsigned bA = (unsigned)row / 17u;
  const int nA = row - (int)bA*17;
  const int xb = (int)(bA - b_lo) * (NNODE*CIN);   // element offset of lane's batch
  const int rowbase = xb + nA*CIN;                 // element offset of lane's row

  // T1,T2 rows for this lane's node (f32, registers; statically indexed)
  float t1[NNODE], t2[NNODE];
  #pragma unroll
  for (int m = 0; m < NNODE; m++){
    t1[m] = Tws[289   + nA*NNODE + m];
    t2[m] = Tws[2*289 + nA*NNODE + m];
  }

  __syncthreads();

  f32x16 acc[4];
  #pragma unroll
  for (int ct = 0; ct < 4; ct++){
    #pragma unroll
    for (int i = 0; i < 16; i++) acc[ct][i] = 0.f;
  }

  #pragma unroll 1
  for (int s = 0; s < 8; s++){
    const int c0 = s*16 + h*8;           // this lane's 8 contraction channels

    // k=0 A-frag: the lane's own x row (T0 = I)
    short8 af0 = *(const short8*)((const char*)xs + swz((rowbase + c0)*2));

    // aggregate k=1,2 for channels c0..c0+7 in one x pass (broadcast LDS reads)
    float f1[8], f2[8];
    #pragma unroll
    for (int j = 0; j < 8; j++){ f1[j] = 0.f; f2[j] = 0.f; }
    #pragma unroll
    for (int m = 0; m < NNODE; m++){
      uint4v xv = *(const uint4v*)((const char*)xs + swz((xb + m*CIN + c0)*2));
      const float a = t1[m], b = t2[m];
      #pragma unroll
      for (int jj = 0; jj < 4; jj++){
        const float lo = bflo(xv[jj]), hi = bfhi(xv[jj]);
        f1[2*jj]   += a * lo;  f1[2*jj+1] += a * hi;
        f2[2*jj]   += b * lo;  f2[2*jj+1] += b * hi;
      }
    }
    short8 af1, af2;
    #pragma unroll
    for (int j = 0; j < 8; j++){
      af1[j] = (short)f2bf(f1[j]);
      af2[j] = (short)f2bf(f2[j]);
    }

    // B-frags: fragment-linear, 16 B/lane, fully coalesced; MFMA 32x32x16
    #pragma unroll
    for (int ct = 0; ct < 4; ct++){
      short8 b0 = *(const short8*)&W2[(size_t)(((0*8 + s)*4 + ct)*64 + lane)*8];
      short8 b1 = *(const short8*)&W2[(size_t)(((1*8 + s)*4 + ct)*64 + lane)*8];
      short8 b2 = *(const short8*)&W2[(size_t)(((2*8 + s)*4 + ct)*64 + lane)*8];
      acc[ct] = __builtin_amdgcn_mfma_f32_32x32x16_bf16(af0, b0, acc[ct], 0, 0, 0);
      acc[ct] = __builtin_amdgcn_mfma_f32_32x32x16_bf16(af1, b1, acc[ct], 0, 0, 0);
      acc[ct] = __builtin_amdgcn_mfma_f32_32x32x16_bf16(af2, b2, acc[ct], 0, 0, 0);
    }
  }

  // epilogue: bias + relu + store.
  // 32x32 C/D layout (m74/m101): col = lane&31, row = (r&3) + 8*(r>>2) + 4*(lane>>5)
  const int row0w = r0blk + wv*32;
  #pragma unroll
  for (int ct = 0; ct < 4; ct++){
    const int d = ct*32 + (lane & 31);
    const float bi = bias[d];
    #pragma unroll
    for (int r = 0; r < 16; r++){
      const int ro = (r & 3) + 8*(r >> 2) + 4*h;
      float v = acc[ct][r] + bi;
      out[(size_t)(row0w + ro)*COUT + d] = v > 0.f ? v : 0.f;
    }
  }
}

extern "C" void kernel_launch(void* const* d_in, const int* in_sizes, int n_in,
                              void* d_out, int out_size, void* d_ws, size_t ws_size,
                              hipStream_t stream){
  const float* x    = (const float*)d_in[0];
  const float* adj  = (const float*)d_in[1];
  const float* w    = (const float*)d_in[2];
  const float* bias = (const float*)d_in[3];
  float* out = (float*)d_out;

  float* Tws = (float*)d_ws;                                    // 867 f32
  unsigned short* W2 = (unsigned short*)((char*)d_ws + 4096);   // 49152 bf16 = 96KB

  hipLaunchKernelGGL(prep_all, dim3(96), dim3(512), 0, stream, adj, w, Tws, W2);
  hipLaunchKernelGGL(cheb_main, dim3(NBLK), dim3(THREADS), 0, stream, x, bias, Tws, W2, out);
}